// Round 4
// baseline (470.946 us; speedup 1.0000x reference)
//
#include <hip/hip_runtime.h>
#include <hip/hip_bf16.h>

// Problem: out[n,o] = x[n,:] . W[o,:] + bias[o] + scale * sum_r (x[n,:].la[a,r,:]) * lb[a,o,:][r]
//          where a = lora_mapping[n]-1 (skip if mapping==0).
// Strategy: fold LoRA into the GEMM K-dim. Build bf16 Xe[16384,2176], We[2048,2176]
//   Xe[:,0:2048]=bf16(x); Xe[n,2048+(a*16+r)] = bf16(scale * x[n].la[a,r])  (one-hot in a)
//   We[:,0:2048]=bf16(W); We[o,2048+(a*16+r)] = bf16(lb[a,o,r])
// Then out = Xe @ We^T + bias — a single uniform bf16 MFMA GEMM, K=2176=34*64.
//
// R1: prep_x scalar+shuffle latency-bound (154us).
// R2 FAILED: 16 parallel accumulators spilled -> 231us.
// R3: u via MFMA all-adapters. 456us (4 kernels).
// R4 NEUTRAL: split prep 5 ways -> 464us (5 kernels).
// R5: conv_prep + ext_gemm -> 400us (3 kernels).
// R6 NEUTRAL: unrolled conv + dbuf ext -> 403us. Kernel-internal restructures
//   don't move the total; fit across R3-R6 suggests ~30us/launch overhead
//   and/or invisible prep slowness (prep never surfaces in top-5).
// R7 (this round): prep chain fused into ONE kernel (3->2 launches).
//   - prep_fused token-blocks: x fp32 tile -> regs -> convert ONCE -> {global
//     Xe base store + swizzled LDS write}; La converted on the fly from
//     L2-hot fp32 lora_a (no La buffer, no Xb re-read: -67MB traffic);
//     MFMA u from LDS; masked/scaled ext-col write. Next-tile loads issued
//     before MFMA (latency hidden under MFMA+barriers).
//   - prep_fused W-blocks: exact-trip unrolled W + lb-ext conversion.
//   - gemm_fused: + bijective XCD-chunked remap (2048=8*256) over the
//     existing supertile swizzle (T1: We re-reads land in same XCD L2).
//   Numerics bit-identical -> absmax must stay exactly 0.0625.

#define D_IN   2048
#define D_OUT  2048
#define NTOK   16384
#define RANK   16
#define NADAPT 8
#define KEXT   2176          // 2048 + 8*16
#define BM     128
#define BN     128
#define BK     64

typedef __attribute__((ext_vector_type(8))) __bf16 bf16x8;
typedef __attribute__((ext_vector_type(8))) unsigned short u16x8;
typedef __attribute__((ext_vector_type(4))) float  f32x4;

__device__ inline unsigned short f2bf(float f) {
    unsigned u = __builtin_bit_cast(unsigned, f);
    u += 0x7fffu + ((u >> 16) & 1u);      // round-to-nearest-even
    return (unsigned short)(u >> 16);
}

__device__ inline u16x8 cvt8(float4 a, float4 b) {
    u16x8 s;
    s[0] = f2bf(a.x); s[1] = f2bf(a.y); s[2] = f2bf(a.z); s[3] = f2bf(a.w);
    s[4] = f2bf(b.x); s[5] = f2bf(b.y); s[6] = f2bf(b.z); s[7] = f2bf(b.w);
    return s;
}

// ---------------------------------------------------------------------------
// prep_fused: the ENTIRE prep in one kernel, two block flavors.
//
// Token flavor (blocks 0..511, 32 tokens each): per 128-wide K-tile,
//   (1) stage x fp32 tile to regs (4 dwordx4/thr) and la fp32 tile
//       (16 dwordx4/thr, L2-hot: la is 1 MB total),
//   (2) convert once; x goes BOTH to global Xe base cols (u16x8, coalesced)
//       and to LDS Xb (XOR-chunk-swizzled for conflict-free b128 reads);
//       la goes to LDS Lat (same swizzle),
//   (3) next tile's loads issued before MFMA (hide HBM latency),
//   (4) 16 MFMA/wave: u[32 tok][128 ext cols]; wave w owns cols w*32..+31
//       = adapters 2w,2w+1 (mask/scale wave-uniform).
//   Epilogue: mask by map[token], scale, write Xe ext cols.
//   u C-layout col=lane&15, row=(lane>>4)*4+reg [m89-verified].
//
// W flavor (blocks 512..783): exact-trip 8-unit unrolled conversion of
//   W -> We base (524288 units) and lb -> We ext (32768 units);
//   272 blocks * 256 thr * 8 = 557056 units exactly.
// ---------------------------------------------------------------------------
__global__ void prep_fused(const float* __restrict__ x, const float* __restrict__ w,
                           const float* __restrict__ la, const float* __restrict__ lb,
                           const int* __restrict__ map, const float* __restrict__ scaling,
                           unsigned short* __restrict__ Xe, unsigned short* __restrict__ We) {
    __shared__ unsigned short Xb[32 * 128];     // 8 KB
    __shared__ unsigned short Lat[128 * 128];   // 32 KB

    int t = threadIdx.x;

    if (blockIdx.x >= 512) {
        // ---------------- W flavor ----------------
        int gid = (blockIdx.x - 512) * 256 + t;          // < 69632
        float4 v0[8], v1[8];
        unsigned short* dst[8];
#pragma unroll
        for (int j = 0; j < 8; ++j) {
            int u = j * 69632 + gid;
            const float* src;
            unsigned short* d;
            if (u < 524288) {                            // W base cols
                int o = u >> 8, kc = (u & 255) * 8;
                src = w + (size_t)o * D_IN + kc;
                d   = We + (size_t)o * KEXT + kc;
            } else {                                     // lb ext cols
                int v = u - 524288;
                int o = v >> 4, m = v & 15;
                int a = m >> 1, r = (m & 1) * 8;
                src = lb + ((size_t)a * D_OUT + o) * RANK + r;
                d   = We + (size_t)o * KEXT + D_IN + m * 8;
            }
            v0[j] = *(const float4*)src;
            v1[j] = *(const float4*)(src + 4);
            dst[j] = d;
        }
#pragma unroll
        for (int j = 0; j < 8; ++j)
            *(u16x8*)dst[j] = cvt8(v0[j], v1[j]);
        return;
    }

    // ---------------- token flavor ----------------
    int lane = t & 63, wave = t >> 6;                    // wave 0..3
    int n0 = blockIdx.x * 32;

    f32x4 acc[2][2] = {};
    float4 xv[4];                                        // 2 slots x 2 dwordx4
    float4 lv[16];                                       // 8 slots x 2

    // preload tile 0
#pragma unroll
    for (int s2 = 0; s2 < 2; ++s2) {
        int s = t + s2 * 256, row = s >> 4, ch = s & 15;
        const float* src = x + (size_t)(n0 + row) * D_IN + ch * 8;
        xv[s2 * 2] = *(const float4*)src;
        xv[s2 * 2 + 1] = *(const float4*)(src + 4);
    }
#pragma unroll
    for (int j = 0; j < 8; ++j) {
        int s = t + j * 256, c = s >> 4, ch = s & 15;
        const float* src = la + (size_t)c * D_IN + ch * 8;
        lv[j * 2] = *(const float4*)src;
        lv[j * 2 + 1] = *(const float4*)(src + 4);
    }

    for (int kt = 0; kt < 16; ++kt) {
        int k0 = kt * 128;
        __syncthreads();                                 // prev MFMA done; LDS free
        // convert + store (x: global base cols AND LDS; la: LDS)
#pragma unroll
        for (int s2 = 0; s2 < 2; ++s2) {
            int s = t + s2 * 256, row = s >> 4, ch = s & 15;
            u16x8 o = cvt8(xv[s2 * 2], xv[s2 * 2 + 1]);
            *(u16x8*)(Xe + (size_t)(n0 + row) * KEXT + k0 + ch * 8) = o;
            *(u16x8*)(Xb + row * 128 + (ch ^ (row & 7)) * 8) = o;
        }
#pragma unroll
        for (int j = 0; j < 8; ++j) {
            int s = t + j * 256, c = s >> 4, ch = s & 15;
            *(u16x8*)(Lat + c * 128 + (ch ^ (c & 7)) * 8) = cvt8(lv[j * 2], lv[j * 2 + 1]);
        }
        // issue next tile's loads now (consumed after next iter's barrier)
        if (kt < 15) {
            int k1 = k0 + 128;
#pragma unroll
            for (int s2 = 0; s2 < 2; ++s2) {
                int s = t + s2 * 256, row = s >> 4, ch = s & 15;
                const float* src = x + (size_t)(n0 + row) * D_IN + k1 + ch * 8;
                xv[s2 * 2] = *(const float4*)src;
                xv[s2 * 2 + 1] = *(const float4*)(src + 4);
            }
#pragma unroll
            for (int j = 0; j < 8; ++j) {
                int s = t + j * 256, c = s >> 4, ch = s & 15;
                const float* src = la + (size_t)c * D_IN + k1 + ch * 8;
                lv[j * 2] = *(const float4*)src;
                lv[j * 2 + 1] = *(const float4*)(src + 4);
            }
        }
        __syncthreads();                                 // LDS tile ready
        // MFMA: u += Xb-tile . Lat-tile^T
#pragma unroll
        for (int ks = 0; ks < 4; ++ks) {
            int chunk = ks * 4 + (lane >> 4);
            int sw = chunk ^ (lane & 7);                 // row&7 == lane&7 (16-aligned)
            bf16x8 af[2], bfr[2];
#pragma unroll
            for (int i = 0; i < 2; ++i)
                af[i] = *(const bf16x8*)(Xb + (i * 16 + (lane & 15)) * 128 + sw * 8);
#pragma unroll
            for (int j = 0; j < 2; ++j)
                bfr[j] = *(const bf16x8*)(Lat + (wave * 32 + j * 16 + (lane & 15)) * 128 + sw * 8);
#pragma unroll
            for (int i = 0; i < 2; ++i)
#pragma unroll
                for (int j = 0; j < 2; ++j)
                    acc[i][j] = __builtin_amdgcn_mfma_f32_16x16x32_bf16(af[i], bfr[j], acc[i][j], 0, 0, 0);
        }
    }

    // epilogue: c = wave*32 + j*16 + colq -> adapter = wave*2 + j (wave-uniform)
    int colq = lane & 15, rq = lane >> 4;
#pragma unroll
    for (int j = 0; j < 2; ++j) {
        int c = wave * 32 + j * 16 + colq;
        int aid = wave * 2 + j + 1;
        float sc = scaling[wave * 2 + j];
#pragma unroll
        for (int i = 0; i < 2; ++i) {
#pragma unroll
            for (int r = 0; r < 4; ++r) {
                int token = n0 + i * 16 + rq * 4 + r;
                unsigned short v = 0;
                if (map[token] == aid) v = f2bf(acc[i][j][r] * sc);
                Xe[(size_t)token * KEXT + D_IN + c] = v;
            }
        }
    }
}

// ---------------------------------------------------------------------------
// Main GEMM: out[M=16384, N=2048] = Xe @ We^T + bias.  m97 structure:
// 128x128 tile, BK=64, 4 waves in 2x2, each wave 64x64 via 4x4 of 16x16x32
// bf16 MFMA, global_load_lds width=16 staging, XOR-swizzled LDS k-chunks
// (swizzle on the global source address; LDS dest stays linear as required
// by global_load_lds). Block remap: XCD-chunked (8 XCDs x 256 blocks) THEN
// supertile decode — each XCD owns 2 contiguous supertile groups so We
// panel re-reads hit the same XCD's L2 (T1, bijective since 2048%8==0).
// ---------------------------------------------------------------------------
__global__ void gemm_fused(const unsigned short* __restrict__ Xe,
                           const unsigned short* __restrict__ We,
                           const float* __restrict__ bias,
                           float* __restrict__ out) {
    __shared__ unsigned short As[BM * BK];               // [128][64] bf16, 16 KB
    __shared__ unsigned short Bs[BN * BK];

    int t = threadIdx.x;
    int lane = t & 63, wave = t >> 6;
    // XCD-chunked remap then supertile swizzle (groups of 8 bm x 16 bn)
    int gb = blockIdx.x;
    int g = (gb & 7) * 256 + (gb >> 3);                  // 2048 = 8 XCD * 256
    int group = g >> 7, within = g & 127;
    int bm = group * 8 + (within & 7);                   // 0..127
    int bn = within >> 3;                                // 0..15

    int wm = wave >> 1, wn = wave & 1;                   // 2x2 wave grid
    f32x4 acc[4][4] = {};

    for (int k0 = 0; k0 < KEXT; k0 += BK) {
        __syncthreads();                                 // prev compute done
#pragma unroll
        for (int c = 0; c < 4; ++c) {
            int linear = (wave * 4 + c) * 64 + lane;     // 16B-chunk id within tile
            int row = linear >> 3;                       // 0..127
            int kc  = linear & 7;                        // 16B chunk within row
            int gc  = kc ^ (row & 7);                    // fetch swizzled source chunk
            const unsigned short* ga = Xe + (size_t)(bm * BM + row) * KEXT + k0 + gc * 8;
            __builtin_amdgcn_global_load_lds(
                (const __attribute__((address_space(1))) unsigned int*)ga,
                (__attribute__((address_space(3))) unsigned int*)(As + (wave * 4 + c) * 512),
                16, 0, 0);
            const unsigned short* gb2 = We + (size_t)(bn * BN + row) * KEXT + k0 + gc * 8;
            __builtin_amdgcn_global_load_lds(
                (const __attribute__((address_space(1))) unsigned int*)gb2,
                (__attribute__((address_space(3))) unsigned int*)(Bs + (wave * 4 + c) * 512),
                16, 0, 0);
        }
        __syncthreads();                                 // staging visible (compiler drains vmcnt)
#pragma unroll
        for (int ks = 0; ks < 2; ++ks) {                 // two K=32 steps per BK=64
            bf16x8 af[4], bfr[4];
            int gchunk = ks * 4 + (lane >> 4);
            int sw = gchunk ^ (lane & 7);                // row&7 == lane&7 for 16-aligned tiles
#pragma unroll
            for (int i = 0; i < 4; ++i) {
                int rowA = wm * 64 + i * 16 + (lane & 15);
                af[i]  = *(const bf16x8*)(As + rowA * BK + sw * 8);
                int rowB = wn * 64 + i * 16 + (lane & 15);
                bfr[i] = *(const bf16x8*)(Bs + rowB * BK + sw * 8);
            }
#pragma unroll
            for (int i = 0; i < 4; ++i)
#pragma unroll
                for (int j = 0; j < 4; ++j)
                    acc[i][j] = __builtin_amdgcn_mfma_f32_16x16x32_bf16(af[i], bfr[j], acc[i][j], 0, 0, 0);
        }
    }

    // epilogue: C/D layout col=lane&15, row=(lane>>4)*4+reg  [m89-verified]
    int colq = lane & 15, rq = lane >> 4;
#pragma unroll
    for (int j = 0; j < 4; ++j) {
        int col = bn * BN + wn * 64 + j * 16 + colq;
        float bv = bias[col];
#pragma unroll
        for (int i = 0; i < 4; ++i) {
            int row0 = bm * BM + wm * 64 + i * 16 + rq * 4;
#pragma unroll
            for (int r = 0; r < 4; ++r)
                out[(size_t)(row0 + r) * D_OUT + col] = acc[i][j][r] + bv;
        }
    }
}

extern "C" void kernel_launch(void* const* d_in, const int* in_sizes, int n_in,
                              void* d_out, int out_size, void* d_ws, size_t ws_size,
                              hipStream_t stream) {
    (void)in_sizes; (void)n_in; (void)out_size; (void)ws_size;
    const float* x       = (const float*)d_in[0];
    const int*   map     = (const int*)d_in[1];
    const float* weight  = (const float*)d_in[2];
    const float* bias    = (const float*)d_in[3];
    const float* lora_a  = (const float*)d_in[4];
    const float* lora_b  = (const float*)d_in[5];
    const float* scaling = (const float*)d_in[6];
    float* out = (float*)d_out;

    unsigned short* Xe = (unsigned short*)d_ws;                    // 16384*2176*2 = 71.3 MB
    unsigned short* We = Xe + (size_t)NTOK * KEXT;                 // + 8.9 MB

    prep_fused<<<784, 256, 0, stream>>>(x, weight, lora_a, lora_b, map, scaling, Xe, We);
    gemm_fused<<<(NTOK / BM) * (D_OUT / BN), 256, 0, stream>>>(Xe, We, bias, out);
}

// Round 5
// 405.715 us; speedup vs baseline: 1.1608x; 1.1608x over previous
//
#include <hip/hip_runtime.h>
#include <hip/hip_bf16.h>

// Problem: out[n,o] = x[n,:] . W[o,:] + bias[o] + scale * sum_r (x[n,:].la[a,r,:]) * lb[a,o,:][r]
//          where a = lora_mapping[n]-1 (skip if mapping==0).
// Strategy: fold LoRA into the GEMM K-dim. Build bf16 Xe[16384,2176], We[2048,2176]
//   Xe[:,0:2048]=bf16(x); Xe[n,2048+(a*16+r)] = bf16(scale * x[n].la[a,r])  (one-hot in a)
//   We[:,0:2048]=bf16(W); We[o,2048+(a*16+r)] = bf16(lb[a,o,r])
// Then out = Xe @ We^T + bias — a single uniform bf16 MFMA GEMM, K=2176=34*64.
//
// R3: 456us (4 kernels). R4: 464 (5 kernels). R5/R6: 400/403 (3 kernels).
// R7 REGRESSION: full prep fusion -> 471. prep_fused surfaced at 161us,
//   latency-bound (HBM 22%, Mfma 2%, Occ 22%).
// COST MODEL (fits R3-R7): dur = F + sum(kernels), F ~= 165us fixed harness
//   overhead (reset memsets); launches ~free. R5/R6 conv+ext ~= 90us (~85%
//   of their ~75us floor); gemm 145.5 (1007 TF effective).
// R8 (this round): revert fusion; exact-launch one-shot conversions
//   (conv_x: 16384 blk x 1 unit/thr; conv_w: 2304 blk covering W+la+lb);
//   ext_gemm verbatim from R6 (proven); gemm keeps m97 structure with a
//   bn-slice-per-XCD remap (each XCD's 1.1MB B-slice stays L2-resident).
//   8-phase 256^2 gemm deliberately deferred (race-screen risk).

#define D_IN   2048
#define D_OUT  2048
#define NTOK   16384
#define RANK   16
#define NADAPT 8
#define KEXT   2176          // 2048 + 8*16
#define BM     128
#define BN     128
#define BK     64
#define EBM    32            // ext_gemm M-tile
#define EBK    128           // ext_gemm K-tile

typedef __attribute__((ext_vector_type(8))) __bf16 bf16x8;
typedef __attribute__((ext_vector_type(8))) unsigned short u16x8;
typedef __attribute__((ext_vector_type(4))) float  f32x4;

__device__ inline unsigned short f2bf(float f) {
    unsigned u = __builtin_bit_cast(unsigned, f);
    u += 0x7fffu + ((u >> 16) & 1u);      // round-to-nearest-even
    return (unsigned short)(u >> 16);
}

__device__ inline u16x8 cvt8(float4 a, float4 b) {
    u16x8 s;
    s[0] = f2bf(a.x); s[1] = f2bf(a.y); s[2] = f2bf(a.z); s[3] = f2bf(a.w);
    s[4] = f2bf(b.x); s[5] = f2bf(b.y); s[6] = f2bf(b.z); s[7] = f2bf(b.w);
    return s;
}

// ---------------------------------------------------------------------------
// conv_x: x[16384][2048] fp32 -> Xe base cols bf16. One float8 unit per
// thread, exact launch (16384 blocks x 256 thr = 4194304 units), no loop.
// Wave reads 2KB contiguous, writes 1KB contiguous. Pure stream.
// ---------------------------------------------------------------------------
__global__ void conv_x(const float* __restrict__ x, unsigned short* __restrict__ Xe) {
    int t = blockIdx.x * 256 + threadIdx.x;
    int n = t >> 8, kc = (t & 255) * 8;
    const float* src = x + (size_t)n * D_IN + kc;
    float4 v0 = *(const float4*)src;
    float4 v1 = *(const float4*)(src + 4);
    *(u16x8*)(Xe + (size_t)n * KEXT + kc) = cvt8(v0, v1);
}

// ---------------------------------------------------------------------------
// conv_w: all small conversions, one unit per thread, exact launch
// (2304 blocks x 256 = 589824 units):
//   [0, 524288):        W[2048][2048] -> We base cols
//   [524288, 557056):   la (contiguous) -> La[128][2048] bf16
//   [557056, 589824):   lb[8][2048][16] -> We ext cols (unit of 8 ext cols
//                       = 8 contiguous source floats; a=m>>1, r=(m&1)*8)
// ---------------------------------------------------------------------------
__global__ void conv_w(const float* __restrict__ w, const float* __restrict__ la,
                       const float* __restrict__ lb,
                       unsigned short* __restrict__ We, unsigned short* __restrict__ La) {
    int u = blockIdx.x * 256 + threadIdx.x;
    const float* src;
    unsigned short* dst;
    if (u < 524288) {
        int o = u >> 8, kc = (u & 255) * 8;
        src = w + (size_t)o * D_IN + kc;
        dst = We + (size_t)o * KEXT + kc;
    } else if (u < 557056) {
        int v = u - 524288;
        src = la + (size_t)v * 8;
        dst = La + (size_t)v * 8;
    } else {
        int v = u - 557056;
        int o = v >> 4, m = v & 15;
        int a = m >> 1, r = (m & 1) * 8;
        src = lb + ((size_t)a * D_OUT + o) * RANK + r;
        dst = We + (size_t)o * KEXT + D_IN + m * 8;
    }
    float4 v0 = *(const float4*)src;
    float4 v1 = *(const float4*)(src + 4);
    *(u16x8*)dst = cvt8(v0, v1);
}

// ---------------------------------------------------------------------------
// ext_gemm: u[n][c] = Xb[n,:] . La[c,:], n in 32-token tiles, c = 0..127.
// BM=32, BN=128, BK=128, 4 waves; wave w owns cols w*32..+31 (adapters 2w,
// 2w+1 -> mask/scale wave-uniform). Double-buffered LDS (80 KB, 2 blk/CU),
// 2-phase pipeline: STAGE(kt+1) issued before compute(kt); the single
// __syncthreads per tile drains vmcnt (compiler semantics), so staging
// latency overlaps the 16 MFMAs + ds_reads of the current tile.
// global_load_lds w=16 with XOR-swizzled SOURCE chunk (gc = kc ^ (row&7)),
// linear LDS dest; ds_read applies the same XOR -> 2-way banks max.
// u C-layout: col=lane&15 (ext col), row=(lane>>4)*4+reg (token) [m89-verified].
// Reads Xe base cols / writes ext cols: disjoint, no hazard. [R6-proven]
// ---------------------------------------------------------------------------
__global__ void ext_gemm(unsigned short* Xe, const int* __restrict__ map,
                         const unsigned short* __restrict__ La,
                         const float* __restrict__ scaling) {
    __shared__ unsigned short As[2][EBM * EBK];          // 2 x 8 KB
    __shared__ unsigned short Bs[2][128 * EBK];          // 2 x 32 KB

    int t = threadIdx.x, lane = t & 63, wave = t >> 6;
    int n0 = blockIdx.x * EBM;

    f32x4 acc[2][2] = {};

    auto stage = [&](int buf, int kt) {
        int k0 = kt * EBK;
#pragma unroll
        for (int c = 0; c < 2; ++c) {                    // A: 512 chunks, 2/thread
            int linear = (wave * 2 + c) * 64 + lane;
            int row = linear >> 4, kc = linear & 15;
            int gc = kc ^ (row & 7);
            const unsigned short* ga = Xe + (size_t)(n0 + row) * KEXT + k0 + gc * 8;
            __builtin_amdgcn_global_load_lds(
                (const __attribute__((address_space(1))) unsigned int*)ga,
                (__attribute__((address_space(3))) unsigned int*)(&As[buf][0] + (wave * 2 + c) * 512),
                16, 0, 0);
        }
#pragma unroll
        for (int c = 0; c < 8; ++c) {                    // B: 2048 chunks, 8/thread
            int linear = (wave * 8 + c) * 64 + lane;
            int row = linear >> 4, kc = linear & 15;
            int gc = kc ^ (row & 7);
            const unsigned short* gb = La + (size_t)row * D_IN + k0 + gc * 8;
            __builtin_amdgcn_global_load_lds(
                (const __attribute__((address_space(1))) unsigned int*)gb,
                (__attribute__((address_space(3))) unsigned int*)(&Bs[buf][0] + (wave * 8 + c) * 512),
                16, 0, 0);
        }
    };

    auto compute = [&](int buf) {
#pragma unroll
        for (int ks = 0; ks < 4; ++ks) {                 // four K=32 steps
            int gchunk = ks * 4 + (lane >> 4);
            int sw = gchunk ^ (lane & 7);                // row&7 == lane&7 (16-aligned tiles)
            bf16x8 af[2], bfr[2];
#pragma unroll
            for (int i = 0; i < 2; ++i)
                af[i] = *(const bf16x8*)(&As[buf][(i * 16 + (lane & 15)) * EBK + sw * 8]);
#pragma unroll
            for (int j = 0; j < 2; ++j)
                bfr[j] = *(const bf16x8*)(&Bs[buf][(wave * 32 + j * 16 + (lane & 15)) * EBK + sw * 8]);
#pragma unroll
            for (int i = 0; i < 2; ++i)
#pragma unroll
                for (int j = 0; j < 2; ++j)
                    acc[i][j] = __builtin_amdgcn_mfma_f32_16x16x32_bf16(af[i], bfr[j], acc[i][j], 0, 0, 0);
        }
    };

    stage(0, 0);
    __syncthreads();                                     // drains vmcnt -> buf0 ready
    int cur = 0;
    for (int kt = 0; kt < D_IN / EBK; ++kt) {            // 16 K-tiles
        if (kt + 1 < D_IN / EBK) stage(cur ^ 1, kt + 1); // prefetch next tile
        compute(cur);                                    // overlap with stage latency
        __syncthreads();                                 // drain vmcnt; readers done
        cur ^= 1;
    }

    // epilogue: c = wave*32 + j*16 + (lane&15) -> adapter a = wave*2 + j (uniform)
    int colq = lane & 15, rq = lane >> 4;
#pragma unroll
    for (int j = 0; j < 2; ++j) {
        int c = wave * 32 + j * 16 + colq;
        int aid = wave * 2 + j + 1;
        float sc = scaling[wave * 2 + j];
#pragma unroll
        for (int i = 0; i < 2; ++i) {
#pragma unroll
            for (int r = 0; r < 4; ++r) {
                int token = n0 + i * 16 + rq * 4 + r;
                unsigned short v = 0;
                if (map[token] == aid) v = f2bf(acc[i][j][r] * sc);
                Xe[(size_t)token * KEXT + D_IN + c] = v;
            }
        }
    }
}

// ---------------------------------------------------------------------------
// Main GEMM: out[M=16384, N=2048] = Xe @ We^T + bias.  m97 structure:
// 128x128 tile, BK=64, 4 waves in 2x2, each wave 64x64 via 4x4 of 16x16x32
// bf16 MFMA, global_load_lds width=16 staging, XOR-swizzled LDS k-chunks
// (swizzle on the global source address; LDS dest stays linear as required
// by global_load_lds).
// Block remap (bn-slice-per-XCD, bijective): hardware round-robins blockIdx
// across 8 XCDs, so xcd = gb&7. XCD x owns bn in {2x, 2x+1} x all bm: its
// We slice (2 x 557KB = 1.1MB) stays resident in that XCD's 4MB L2 for the
// whole kernel; consecutive idx share bm so the A-tile gets immediate L2
// reuse. Xe streams via L3.
// ---------------------------------------------------------------------------
__global__ void gemm_fused(const unsigned short* __restrict__ Xe,
                           const unsigned short* __restrict__ We,
                           const float* __restrict__ bias,
                           float* __restrict__ out) {
    __shared__ unsigned short As[BM * BK];               // [128][64] bf16, 16 KB
    __shared__ unsigned short Bs[BN * BK];

    int t = threadIdx.x;
    int lane = t & 63, wave = t >> 6;
    int gb = blockIdx.x;
    int xcd = gb & 7, idx = gb >> 3;                     // 2048 = 8 XCD * 256
    int bm = idx >> 1;                                   // 0..127
    int bn = xcd * 2 + (idx & 1);                        // 0..15

    int wm = wave >> 1, wn = wave & 1;                   // 2x2 wave grid
    f32x4 acc[4][4] = {};

    for (int k0 = 0; k0 < KEXT; k0 += BK) {
        __syncthreads();                                 // prev compute done
#pragma unroll
        for (int c = 0; c < 4; ++c) {
            int linear = (wave * 4 + c) * 64 + lane;     // 16B-chunk id within tile
            int row = linear >> 3;                       // 0..127
            int kc  = linear & 7;                        // 16B chunk within row
            int gc  = kc ^ (row & 7);                    // fetch swizzled source chunk
            const unsigned short* ga = Xe + (size_t)(bm * BM + row) * KEXT + k0 + gc * 8;
            __builtin_amdgcn_global_load_lds(
                (const __attribute__((address_space(1))) unsigned int*)ga,
                (__attribute__((address_space(3))) unsigned int*)(As + (wave * 4 + c) * 512),
                16, 0, 0);
            const unsigned short* gb2 = We + (size_t)(bn * BN + row) * KEXT + k0 + gc * 8;
            __builtin_amdgcn_global_load_lds(
                (const __attribute__((address_space(1))) unsigned int*)gb2,
                (__attribute__((address_space(3))) unsigned int*)(Bs + (wave * 4 + c) * 512),
                16, 0, 0);
        }
        __syncthreads();                                 // staging visible (compiler drains vmcnt)
#pragma unroll
        for (int ks = 0; ks < 2; ++ks) {                 // two K=32 steps per BK=64
            bf16x8 af[4], bfr[4];
            int gchunk = ks * 4 + (lane >> 4);
            int sw = gchunk ^ (lane & 7);                // row&7 == lane&7 for 16-aligned tiles
#pragma unroll
            for (int i = 0; i < 4; ++i) {
                int rowA = wm * 64 + i * 16 + (lane & 15);
                af[i]  = *(const bf16x8*)(As + rowA * BK + sw * 8);
                int rowB = wn * 64 + i * 16 + (lane & 15);
                bfr[i] = *(const bf16x8*)(Bs + rowB * BK + sw * 8);
            }
#pragma unroll
            for (int i = 0; i < 4; ++i)
#pragma unroll
                for (int j = 0; j < 4; ++j)
                    acc[i][j] = __builtin_amdgcn_mfma_f32_16x16x32_bf16(af[i], bfr[j], acc[i][j], 0, 0, 0);
        }
    }

    // epilogue: C/D layout col=lane&15, row=(lane>>4)*4+reg  [m89-verified]
    int colq = lane & 15, rq = lane >> 4;
#pragma unroll
    for (int j = 0; j < 4; ++j) {
        int col = bn * BN + wn * 64 + j * 16 + colq;
        float bv = bias[col];
#pragma unroll
        for (int i = 0; i < 4; ++i) {
            int row0 = bm * BM + wm * 64 + i * 16 + rq * 4;
#pragma unroll
            for (int r = 0; r < 4; ++r)
                out[(size_t)(row0 + r) * D_OUT + col] = acc[i][j][r] + bv;
        }
    }
}

extern "C" void kernel_launch(void* const* d_in, const int* in_sizes, int n_in,
                              void* d_out, int out_size, void* d_ws, size_t ws_size,
                              hipStream_t stream) {
    (void)in_sizes; (void)n_in; (void)out_size; (void)ws_size;
    const float* x       = (const float*)d_in[0];
    const int*   map     = (const int*)d_in[1];
    const float* weight  = (const float*)d_in[2];
    const float* bias    = (const float*)d_in[3];
    const float* lora_a  = (const float*)d_in[4];
    const float* lora_b  = (const float*)d_in[5];
    const float* scaling = (const float*)d_in[6];
    float* out = (float*)d_out;

    unsigned short* Xe = (unsigned short*)d_ws;                    // 16384*2176*2 = 71.3 MB
    unsigned short* We = Xe + (size_t)NTOK * KEXT;                 // + 8.9 MB
    unsigned short* La = We + (size_t)D_OUT * KEXT;                // + 0.5 MB bf16 [128][2048]

    conv_x<<<NTOK, 256, 0, stream>>>(x, Xe);
    conv_w<<<2304, 256, 0, stream>>>(weight, lora_a, lora_b, We, La);
    ext_gemm<<<NTOK / EBM, 256, 0, stream>>>(Xe, map, La, scaling);
    gemm_fused<<<(NTOK / BM) * (D_OUT / BN), 256, 0, stream>>>(Xe, We, bias, out);
}